// Round 6
// baseline (1131.437 us; speedup 1.0000x reference)
//
#include <hip/hip_runtime.h>
#include <hip/hip_bf16.h>
#include <cstdint>
#include <cmath>

// ---------------------------------------------------------------------------
// TransLayer block: fused QKV proj -> softmax(QK^T/sqrt(D)) V -> GELU FFN.
// B=8, N=2048, D=1028 (K-pad 1088 = 17*64, N-pad 1152), H=4112 (pad 4224).
// GEMMs: C = A @ B^T, K-contiguous bf16, fp32 acc, MFMA 16x16x32.
// R6: 256x128 tile (BM=256, BN=128), BK=64, m97 protocol (stage ->
// __syncthreads -> compute -> __syncthreads), 4 waves/block, per-wave output
// 128x64 = acc[8][4] (128 AGPR).  Rationale: all prior rounds sit on a
// ~15 B/cyc/CU staged-bytes supply ceiling; TF = supply x intensity.
// 128x128 tile = 64 FLOP/B -> 590 TF (measured R0/R5).  256x128 = 85.3
// FLOP/B with 2 blocks/CU retained (8 waves x ~192 regs <= 2048; LDS
// 48 KiB x 2 = 96 <= 160) -> predicted ~780 TF.  Numerics bit-identical
// to R0/R5 (same accumulation order).  LDS XOR-swizzle (0 conflicts).
// FFN runs in 8192-row chunks so Hb (69 MB) stays L3-resident for FFN2.
// ---------------------------------------------------------------------------

typedef __bf16 bf16;
typedef __bf16 bf16x8 __attribute__((ext_vector_type(8)));
typedef float  f32x4  __attribute__((ext_vector_type(4)));

#define D_REAL   1028
#define D_PADK   1088   // K-dim pad (mult of 64)
#define D_PADN   1152
#define H_REAL   4112
#define H_PAD    4224   // 66*64
#define NTOK     2048
#define NB       8
#define MTOT     (NB*NTOK)               // 16384
#define SLAB_X   ((size_t)NTOK*D_PADK)   // 2,228,224 elems
#define SLAB_S   ((size_t)NTOK*NTOK)
#define WSLAB    ((size_t)D_PADN*D_PADK) // 1,253,376 elems
#define VSLAB    ((size_t)D_PADN*NTOK)

__device__ __forceinline__ void async16(const void* g, void* l) {
    __builtin_amdgcn_global_load_lds(
        (__attribute__((address_space(1))) void*)(uintptr_t)g,
        (__attribute__((address_space(3))) void*)(uint32_t)(uintptr_t)l,
        16, 0, 0);
}

// EPI: 0 = bf16 out (+bias), 3 = gelu(acc+bias)->bf16, 4 = fp32 acc+bias+resid,
//      5 = fused QKV (Q/K to slabs, V transposed to OutV), 6 = bf16 out*scale
template <int EPI, bool XPIN>
__global__ __launch_bounds__(256, 2)
void gemm_bt(const bf16* __restrict__ A, size_t strideA,
             const bf16* __restrict__ B, size_t strideB,
             const float* __restrict__ bias, size_t strideBias,
             void* __restrict__ Out, size_t strideOut,
             bf16* __restrict__ OutV,
             int K, int outPitch, int colBound, float scale,
             const float* __restrict__ resid)
{
    __shared__ __attribute__((aligned(16))) bf16 tA[256 * 64];  // 32 KB
    __shared__ __attribute__((aligned(16))) bf16 tB[128 * 64];  // 16 KB

    int bx, by, bz;
    if (XPIN) { bz = blockIdx.x; by = blockIdx.y; bx = blockIdx.z; }
    else      { bx = blockIdx.x; by = blockIdx.y; bz = blockIdx.z; }

    A += (size_t)bz * strideA;
    B += (size_t)bz * strideB;
    if (bias) bias += (size_t)bz * strideBias;

    const int tid  = threadIdx.x;
    const int lane = tid & 63;
    const int wv   = tid >> 6;       // 0..3
    const int wm   = wv >> 1;        // 0..1 (M half: 128 rows)
    const int wn   = wv & 1;         // 0..1 (N half: 64 cols)

    f32x4 acc[8][4] = {};

    // staging: wave wv covers A rows [wv*64, wv*64+64) via 8 async16 and
    // B rows [wv*32, wv*32+32) via 4 async16.  Each async16 covers 8 rows
    // (64 lanes x 16B).  Lane L -> row L>>3, LDS slot L&7, sourcing global
    // chunk (L&7)^((L>>3)&7) of that row, so LDS(row,slot) =
    // global(row, slot^(row&7)).
    const int sRow = lane >> 3;
    const int sCh  = (lane & 7) ^ sRow;
    const bf16* gA = A + (size_t)(by * 256 + wv * 64 + sRow) * K + sCh * 8;
    const bf16* gB = B + (size_t)(bx * 128 + wv * 32 + sRow) * K + sCh * 8;
    bf16* lA = &tA[(wv * 64) * 64];
    bf16* lB = &tB[(wv * 32) * 64];

    const int lr  = lane & 15;
    const int lq  = lane >> 4;
    const int rsw = lr & 7;              // row swizzle bits

    for (int k0 = 0; k0 < K; k0 += 64) {
        async16(gA,                  lA);
        async16(gA + (size_t) 8 * K, lA +  8 * 64);
        async16(gA + (size_t)16 * K, lA + 16 * 64);
        async16(gA + (size_t)24 * K, lA + 24 * 64);
        async16(gA + (size_t)32 * K, lA + 32 * 64);
        async16(gA + (size_t)40 * K, lA + 40 * 64);
        async16(gA + (size_t)48 * K, lA + 48 * 64);
        async16(gA + (size_t)56 * K, lA + 56 * 64);
        async16(gB,                  lB);
        async16(gB + (size_t) 8 * K, lB +  8 * 64);
        async16(gB + (size_t)16 * K, lB + 16 * 64);
        async16(gB + (size_t)24 * K, lB + 24 * 64);
        gA += 64; gB += 64;
        __syncthreads();

        #pragma unroll
        for (int kk = 0; kk < 2; ++kk) {
            const int sl = ((kk * 4 + lq) ^ rsw) << 3;   // element offset
            bf16x8 bfr[4];
            #pragma unroll
            for (int j = 0; j < 4; ++j)
                bfr[j] = *(const bf16x8*)&tB[(wn * 64 + j * 16 + lr) * 64 + sl];
            #pragma unroll
            for (int i = 0; i < 8; ++i) {
                const bf16x8 af = *(const bf16x8*)&tA[(wm * 128 + i * 16 + lr) * 64 + sl];
                #pragma unroll
                for (int j = 0; j < 4; ++j)
                    acc[i][j] = __builtin_amdgcn_mfma_f32_16x16x32_bf16(
                        af, bfr[j], acc[i][j], 0, 0, 0);
            }
        }
        __syncthreads();
    }

    // C/D layout: col = lane&15, row = (lane>>4)*4 + reg  [m89/m91]
    #pragma unroll
    for (int i = 0; i < 8; ++i) {
        #pragma unroll
        for (int j = 0; j < 4; ++j) {
            f32x4 v = acc[i][j];
            const int cg = bx * 128 + wn * 64 + j * 16 + lr;
            if (cg >= colBound) continue;
            const int rowBase = by * 256 + wm * 128 + i * 16 + lq * 4;
            const float bs = bias ? bias[cg] : 0.0f;
            #pragma unroll
            for (int r = 0; r < 4; ++r) {
                const int mg = rowBase + r;
                const float val = v[r];
                if (EPI == 0) {
                    ((bf16*)Out + (size_t)bz * strideOut)[(size_t)mg * outPitch + cg] =
                        (bf16)(val + bs);
                } else if (EPI == 3) {
                    const float u = val + bs;
                    const float g = 0.5f * u * (1.0f + erff(u * 0.70710678118654752f));
                    ((bf16*)Out)[(size_t)mg * outPitch + cg] = (bf16)g;
                } else if (EPI == 4) {
                    ((float*)Out)[(size_t)mg * outPitch + cg] =
                        val + bs + resid[(size_t)mg * outPitch + cg];
                } else if (EPI == 5) {
                    const int grp = cg / D_PADN;          // 0=Q,1=K,2=V
                    const int c   = cg - grp * D_PADN;
                    const float u = val + bs;
                    if (grp < 2) {
                        if (c < D_PADK)
                            ((bf16*)Out)[(size_t)bz * 2 * SLAB_X + (size_t)grp * SLAB_X +
                                         (size_t)mg * D_PADK + c] = (bf16)u;
                    } else {
                        OutV[(size_t)bz * VSLAB + (size_t)c * NTOK + mg] = (bf16)u;
                    }
                } else { // EPI == 6
                    ((bf16*)Out + (size_t)bz * strideOut)[(size_t)mg * outPitch + cg] =
                        (bf16)(val * scale);
                }
            }
        }
    }
}

// fp32 [R,C] -> zero-padded bf16 [gridDim.y, CP]
__global__ __launch_bounds__(256)
void cvt_pad(const float* __restrict__ src, int R, int C,
             bf16* __restrict__ dst, int CP)
{
    const int c = blockIdx.x * 256 + threadIdx.x;
    const int r = blockIdx.y;
    if (c >= CP) return;
    const float v = (r < R && c < C) ? src[(size_t)r * C + c] : 0.0f;
    dst[(size_t)r * CP + c] = (bf16)v;
}

__global__ __launch_bounds__(256)
void pad_bias(const float* __restrict__ src, int n, float* __restrict__ dst, int np)
{
    const int i = blockIdx.x * 256 + threadIdx.x;
    if (i < np) dst[i] = (i < n) ? src[i] : 0.0f;
}

// in-place row softmax over 2048 bf16 logits; one wave per row
__global__ __launch_bounds__(256)
void softmax_ip(bf16* __restrict__ S)
{
    const int row  = blockIdx.x * 4 + (threadIdx.x >> 6);
    const int lane = threadIdx.x & 63;
    bf16* s = S + (size_t)row * NTOK + lane * 8;

    float v[32];
    #pragma unroll
    for (int j = 0; j < 4; ++j) {
        bf16x8 t = *(const bf16x8*)(s + j * 512);
        #pragma unroll
        for (int e = 0; e < 8; ++e) v[j * 8 + e] = (float)t[e];
    }
    float m = -1e30f;
    #pragma unroll
    for (int i = 0; i < 32; ++i) m = fmaxf(m, v[i]);
    #pragma unroll
    for (int off = 32; off > 0; off >>= 1) m = fmaxf(m, __shfl_xor(m, off, 64));

    float sum = 0.0f;
    #pragma unroll
    for (int i = 0; i < 32; ++i) { v[i] = __expf(v[i] - m); sum += v[i]; }
    #pragma unroll
    for (int off = 32; off > 0; off >>= 1) sum += __shfl_xor(sum, off, 64);
    const float inv = 1.0f / sum;

    #pragma unroll
    for (int j = 0; j < 4; ++j) {
        bf16x8 t;
        #pragma unroll
        for (int e = 0; e < 8; ++e) t[e] = (bf16)(v[j * 8 + e] * inv);
        *(bf16x8*)(s + j * 512) = t;
    }
}

// ---------------------------------------------------------------------------
// fixed workspace (bytes):
//   WQKV(3*1152x1088 bf16) 0..7,520,256   WE(4224x1088) ..16,711,680
//   WO(1152x4224) ..26,443,776  BQKV ..26,457,600  BE ..26,474,496
//   XBF(16384x1088; attn overwrites in place) ..62,126,080
//   VT(8x1152x2048) ..99,874,816 = OFF_SCR.  Scratch adaptive.
// ---------------------------------------------------------------------------
#define OFF_WQKV   0u
#define OFF_WE     7520256u
#define OFF_WO     16711680u
#define OFF_BQKV   26443776u
#define OFF_BE     26457600u
#define OFF_XBF    26474496u
#define OFF_VT     62126080u
#define OFF_SCR    99874816u
#define QS_BYTES   8912896u     // per-batch Q+K slabs (2 * 2048*1088 * 2B)
#define SS_BYTES   8388608u     // per-batch bf16 score slab

extern "C" void kernel_launch(void* const* d_in, const int* in_sizes, int n_in,
                              void* d_out, int out_size, void* d_ws, size_t ws_size,
                              hipStream_t stream)
{
    const float* x  = (const float*)d_in[0];
    const float* Wq = (const float*)d_in[1];
    const float* bq = (const float*)d_in[2];
    const float* Wk = (const float*)d_in[3];
    const float* bk = (const float*)d_in[4];
    const float* Wv = (const float*)d_in[5];
    const float* bv = (const float*)d_in[6];
    const float* We = (const float*)d_in[7];
    const float* be = (const float*)d_in[8];
    const float* Wo = (const float*)d_in[9];
    const float* bo = (const float*)d_in[10];

    char* ws = (char*)d_ws;
    bf16*  Wqkv = (bf16*)(ws + OFF_WQKV);
    bf16*  WeP  = (bf16*)(ws + OFF_WE);
    bf16*  WoP  = (bf16*)(ws + OFF_WO);
    float* Bqkv = (float*)(ws + OFF_BQKV);
    float* BeP  = (float*)(ws + OFF_BE);
    bf16*  Xbf  = (bf16*)(ws + OFF_XBF);
    bf16*  Vt   = (bf16*)(ws + OFF_VT);
    char*  scr  = ws + OFF_SCR;

    const size_t avail = ws_size > OFF_SCR ? ws_size - OFF_SCR : 0;
    const size_t perG  = (size_t)QS_BYTES + SS_BYTES;   // 17,301,504
    int G = (avail >= 8 * perG) ? 8 : (avail >= 4 * perG) ? 4
          : (avail >= 2 * perG) ? 2 : 1;
    // FFN chunk rows: keep Hb (R*4224*2 B) L3-resident; 8192 -> 69 MB.
    int R = (avail >= 69206016u) ? 8192 : (avail >= 34603008u) ? 4096 : 2048;

    bf16* Qs = (bf16*)scr;                                // [G][2] Q,K slabs
    bf16* Ss = (bf16*)(scr + (size_t)G * QS_BYTES);       // [G] score slabs
    bf16* Hb = (bf16*)scr;                                // FFN phase alias

    const dim3 blk(256);
    const float inv_sqrt_d = (float)(1.0 / sqrt((double)D_REAL));

    // ---- convert + pad to bf16 ----
    cvt_pad<<<dim3(5, MTOT), blk, 0, stream>>>(x, MTOT, D_REAL, Xbf, D_PADK);
    cvt_pad<<<dim3(5, D_PADN), blk, 0, stream>>>(Wq, D_REAL, D_REAL, Wqkv, D_PADK);
    cvt_pad<<<dim3(5, D_PADN), blk, 0, stream>>>(Wk, D_REAL, D_REAL, Wqkv + WSLAB, D_PADK);
    cvt_pad<<<dim3(5, D_PADN), blk, 0, stream>>>(Wv, D_REAL, D_REAL, Wqkv + 2 * WSLAB, D_PADK);
    cvt_pad<<<dim3(5, H_PAD), blk, 0, stream>>>(We, H_REAL, D_REAL, WeP, D_PADK);
    cvt_pad<<<dim3(17, D_PADN), blk, 0, stream>>>(Wo, D_REAL, H_REAL, WoP, H_PAD);
    pad_bias<<<dim3(5), blk, 0, stream>>>(bq, D_REAL, Bqkv, D_PADN);
    pad_bias<<<dim3(5), blk, 0, stream>>>(bk, D_REAL, Bqkv + D_PADN, D_PADN);
    pad_bias<<<dim3(5), blk, 0, stream>>>(bv, D_REAL, Bqkv + 2 * D_PADN, D_PADN);
    pad_bias<<<dim3(17), blk, 0, stream>>>(be, H_REAL, BeP, H_PAD);

    // ---- attention, G batches per iteration ----
    for (int g0 = 0; g0 < NB; g0 += G) {
        // fused QKV projection: cols [0,1152)=Q, [1152,2304)=K, [2304,3456)=V^T
        // 27 col tiles x 128 = 3456 exact; 8 row tiles x 256 = 2048 exact.
        gemm_bt<5, false><<<dim3(27, 8, G), blk, 0, stream>>>(
            Xbf + (size_t)g0 * SLAB_X, SLAB_X, Wqkv, 0, Bqkv, 0,
            Qs, 0, Vt + (size_t)g0 * VSLAB,
            D_PADK, 0, 3456, 1.0f, nullptr);
        // scores (bf16, scaled): XCD-pinned, batch fastest
        gemm_bt<6, true><<<dim3(G, 8, 16), blk, 0, stream>>>(
            Qs, 2 * SLAB_X, Qs + SLAB_X, 2 * SLAB_X, nullptr, 0,
            Ss, SLAB_S, nullptr, D_PADK, NTOK, NTOK, inv_sqrt_d, nullptr);
        // in-place softmax
        softmax_ip<<<dim3(G * 512), blk, 0, stream>>>(Ss);
        // attn = W @ Vt^T -> overwrite Xbf slab; XCD-pinned
        // 9 col tiles x 128 = 1152 cover D_PADK=1088 (masked; Vt has 1152 rows)
        gemm_bt<0, true><<<dim3(G, 8, 9), blk, 0, stream>>>(
            Ss, SLAB_S, Vt + (size_t)g0 * VSLAB, VSLAB, nullptr, 0,
            Xbf + (size_t)g0 * SLAB_X, SLAB_X, nullptr,
            NTOK, D_PADK, D_PADK, 1.0f, nullptr);
    }

    // ---- FFN in R-row chunks (Hb stays L3-resident) ----
    for (int r0 = 0; r0 < MTOT; r0 += R) {
        gemm_bt<3, false><<<dim3(33, R / 256, 1), blk, 0, stream>>>(
            Xbf + (size_t)r0 * D_PADK, 0, WeP, 0, BeP, 0,
            Hb, 0, nullptr, D_PADK, H_PAD, H_PAD, 1.0f, nullptr);
        gemm_bt<4, false><<<dim3(9, R / 256, 1), blk, 0, stream>>>(
            Hb, 0, WoP, 0, bo, 0,
            (float*)d_out + (size_t)r0 * D_REAL, 0, nullptr,
            H_PAD, D_REAL, D_REAL, 1.0f, x + (size_t)r0 * D_REAL);
    }
}